// Round 7
// baseline (625.445 us; speedup 1.0000x reference)
//
#include <hip/hip_runtime.h>
#include <hip/hip_bf16.h>

typedef unsigned short u16;
typedef __attribute__((ext_vector_type(4))) unsigned short u16x4;
typedef __attribute__((ext_vector_type(8))) unsigned short u16x8;
typedef __attribute__((ext_vector_type(8))) short bf16x8;
typedef __attribute__((ext_vector_type(4))) float f32x4;

__device__ __forceinline__ u16 f2bs(float f) {
    union { float f; unsigned int u; } x; x.f = f;
    unsigned int r = x.u + 0x7FFFu + ((x.u >> 16) & 1u);   // RNE
    return (u16)(r >> 16);
}
__device__ __forceinline__ float bs2f(u16 u) {
    union { unsigned int u; float f; } x; x.u = ((unsigned int)u) << 16; return x.f;
}
__device__ __forceinline__ float lrelu(float e) { return e >= 0.f ? e : 0.2f * e; }

// async global->LDS, 16B per lane; lds dest must be wave-uniform base (HW adds lane*16)
__device__ __forceinline__ void glds16(const void* g, void* l) {
    __builtin_amdgcn_global_load_lds(
        (const __attribute__((address_space(1))) unsigned int*)g,
        (__attribute__((address_space(3))) unsigned int*)l, 16, 0, 0);
}

// ---------------- CSR build ----------------
__global__ void deg_kernel(const int* __restrict__ dst, int* __restrict__ deg, int E) {
    int i = blockIdx.x * 256 + threadIdx.x;
    if (i < E) atomicAdd(&deg[dst[i]], 1);
}

// hierarchical scan: local (1024/block) -> carry scan -> fixup
__global__ __launch_bounds__(1024) void scan_local(const int* __restrict__ deg,
        int* __restrict__ ptr, int* __restrict__ bsum, int N) {
    __shared__ int wsum[16];
    const int t = threadIdx.x, i = blockIdx.x * 1024 + t;
    const int lane = t & 63, w = t >> 6;
    int v = (i < N) ? deg[i] : 0;
    int x = v;
    #pragma unroll
    for (int off = 1; off < 64; off <<= 1) { int y = __shfl_up(x, off); if (lane >= off) x += y; }
    if (lane == 63) wsum[w] = x;
    __syncthreads();
    if (w == 0) {
        int s = (lane < 16) ? wsum[lane] : 0;
        #pragma unroll
        for (int off = 1; off < 16; off <<= 1) { int y = __shfl_up(s, off); if (lane >= off) s += y; }
        if (lane < 16) wsum[lane] = s;
    }
    __syncthreads();
    int incl = x + (w > 0 ? wsum[w - 1] : 0);
    if (i < N) ptr[i + 1] = incl;            // local inclusive; fixed by scan_final
    if (t == 0) bsum[blockIdx.x] = wsum[15];
}

__global__ __launch_bounds__(64) void scan_carry(int* __restrict__ bsum, int nb) {
    int t = threadIdx.x;
    int v = (t < nb) ? bsum[t] : 0;
    int x = v;
    #pragma unroll
    for (int off = 1; off < 64; off <<= 1) { int y = __shfl_up(x, off); if (t >= off) x += y; }
    if (t < nb) bsum[t] = x - v;             // exclusive
}

__global__ __launch_bounds__(1024) void scan_final(const int* __restrict__ deg,
        int* __restrict__ ptr, int* __restrict__ cur, const int* __restrict__ bsum, int N) {
    int i = blockIdx.x * 1024 + threadIdx.x;
    if (i == 0) ptr[0] = 0;
    if (i < N) {
        int p = ptr[i + 1] + bsum[blockIdx.x];
        ptr[i + 1] = p;
        cur[i] = p - deg[i];
    }
}

__global__ void fill_kernel(const int* __restrict__ src, const int* __restrict__ dst,
        int* __restrict__ cur, int* __restrict__ csr, int E) {
    int i = blockIdx.x * 256 + threadIdx.x;
    if (i < E) { int p = atomicAdd(&cur[dst[i]], 1); csr[p] = src[i]; }
}

// ---------------- graph boundary index (batch is sorted) ----------------
__global__ void bounds_kernel(const int* __restrict__ batch, int* __restrict__ gstart,
        int N, int G) {
    int i = blockIdx.x * 256 + threadIdx.x;
    if (i > N) return;
    if (i == 0) {
        int b0 = batch[0];
        for (int g = 0; g <= b0; g++) gstart[g] = 0;
    } else if (i == N) {
        int bl = batch[N - 1];
        for (int g = bl + 1; g <= G; g++) gstart[g] = N;
    } else {
        int b = batch[i], bp = batch[i - 1];
        for (int g = bp + 1; g <= b; g++) gstart[g] = i;
    }
}

// ---------------- weight transpose: fp32 W[K][Nn] -> bf16 Wt[Nn][KT] (zero-pad k>=K) ----
__global__ void transpose_w(const float* __restrict__ W, u16* __restrict__ Wt,
        int K, int Nn, int KT) {
    int idx = blockIdx.x * 256 + threadIdx.x;
    if (idx >= Nn * KT) return;
    int n = idx / KT, k = idx - n * KT;
    Wt[(size_t)n * KT + k] = (k < K) ? f2bs(W[(size_t)k * Nn + n]) : (u16)0;
}

// ---------------- x fp32[775] -> bf16[800] padded (output-centric, 8B stores) --------
__global__ __launch_bounds__(256) void conv_x(const float* __restrict__ x,
        u16* __restrict__ xbf, int N) {
    const int idx = blockIdx.x * 256 + threadIdx.x;   // one thread per 4 outputs
    if (idx >= N * 200) return;                       // 800/4 chunks per row
    const int r = idx / 200;
    const int k4 = (idx - r * 200) * 4;
    const float* row = x + (size_t)r * 775;
    u16x4 o;
    #pragma unroll
    for (int u = 0; u < 4; u++) {
        const int k = k4 + u;
        o[u] = (k < 775) ? f2bs(row[k]) : (u16)0;
    }
    *(u16x4*)&xbf[(size_t)r * 800 + k4] = o;
}

// ---------------- GEMM: C[M,256] bf16 = A[M,K]bf16 @ Wt^T --------------------------
// m97 structure: 128x128 tile, 256 threads, 4 waves of 64x64 (acc[4][4]), BK=32,
// linear [128][32] LDS filled by global_load_lds width=16 (no VGPR round-trip),
// 2 barriers per K-step. k-slot XOR swizzle applied BOTH at the global source
// (stage time) and at the ds_read slot (T2 both-sides rule) -> ~2-way conflicts.
// K must be a multiple of 32 and A padded to K (xbf: 800; act: 256).
__global__ __launch_bounds__(256) void gemm_glds(
        const u16* __restrict__ A, int lda, int M, int K,
        const u16* __restrict__ B, int ldb,
        u16* __restrict__ C, int ldc) {
    __shared__ u16 Alds[128][32];
    __shared__ u16 Blds[128][32];
    const int t = threadIdx.x;
    const int col0 = blockIdx.x * 128;
    const int row0 = blockIdx.y * 128;
    const int wid = t >> 6, lane = t & 63;
    const int wm = wid >> 1, wn = wid & 1;
    const int quad = lane >> 4, l16 = lane & 15;

    f32x4 acc[4][4];
    f32x4 z = {0.f, 0.f, 0.f, 0.f};
    #pragma unroll
    for (int i = 0; i < 4; i++)
        #pragma unroll
        for (int j = 0; j < 4; j++) acc[i][j] = z;

    // staging coords: chunk c: tile row tr = wid*32 + c*16 + (lane>>2), slot = lane&3.
    // LDS slot s at row tr receives global k-chunk (s ^ ((tr>>1)&3)).
    const int trb = wid * 32 + (lane >> 2);
    const int kTiles = K >> 5;
    for (int kt = 0; kt < kTiles; ++kt) {
        const int k0 = kt << 5;
        #pragma unroll
        for (int c = 0; c < 2; c++) {
            const int tr = trb + c * 16;
            const int ks = ((lane & 3) ^ ((tr >> 1) & 3)) * 8;   // swizzled source chunk
            int gra = row0 + tr; if (gra > M - 1) gra = M - 1;   // clamp: junk rows unused
            glds16(A + (size_t)gra * lda + k0 + ks, &Alds[wid * 32 + c * 16][0]);
            glds16(B + (size_t)(col0 + tr) * ldb + k0 + ks, &Blds[wid * 32 + c * 16][0]);
        }
        __syncthreads();                    // vmcnt drained -> tiles visible
        bf16x8 af[4], bfr[4];
        #pragma unroll
        for (int it = 0; it < 4; it++) {
            const int r = wm * 64 + it * 16 + l16;
            af[it] = *(const bf16x8*)&Alds[r][(quad ^ ((r >> 1) & 3)) * 8];
        }
        #pragma unroll
        for (int jt = 0; jt < 4; jt++) {
            const int r = wn * 64 + jt * 16 + l16;
            bfr[jt] = *(const bf16x8*)&Blds[r][(quad ^ ((r >> 1) & 3)) * 8];
        }
        #pragma unroll
        for (int it = 0; it < 4; it++)
            #pragma unroll
            for (int jt = 0; jt < 4; jt++)
                acc[it][jt] = __builtin_amdgcn_mfma_f32_16x16x32_bf16(af[it], bfr[jt], acc[it][jt], 0, 0, 0);
        __syncthreads();                    // compute done -> safe to overwrite
    }
    #pragma unroll
    for (int it = 0; it < 4; it++) {
        int gr0 = row0 + wm * 64 + it * 16 + quad * 4;
        #pragma unroll
        for (int jt = 0; jt < 4; jt++) {
            int gc = col0 + wn * 64 + jt * 16 + l16;
            #pragma unroll
            for (int r = 0; r < 4; r++) {
                int gr = gr0 + r;
                if (gr < M) C[(size_t)gr * ldc + gc] = f2bs(acc[it][jt][r]);
            }
        }
    }
}

// GEMM for layer3: C[M,32] fp32 = A[M,256]bf16 @ Wt3^T (h3 stays fp32 — tiny)
__global__ __launch_bounds__(256) void gemm32(
        const u16* __restrict__ A, int lda, int M, int K,
        const u16* __restrict__ B, int ldb, float* __restrict__ C) {
    __shared__ u16 Alds[128][40];
    __shared__ u16 Blds[32][40];
    const int t = threadIdx.x;
    const int row0 = blockIdx.x * 128;
    const int wid = t >> 6, lane = t & 63;
    const int quad = lane >> 4, l16 = lane & 15;
    f32x4 acc[2][2];
    f32x4 z = {0.f, 0.f, 0.f, 0.f};
    acc[0][0] = z; acc[0][1] = z; acc[1][0] = z; acc[1][1] = z;
    const int kTiles = K >> 5;
    for (int kt = 0; kt < kTiles; ++kt) {
        const int k0 = kt << 5;
        #pragma unroll
        for (int c = 0; c < 2; c++) {
            int ch = t + c * 256;
            int r = ch >> 2, cp = (ch & 3) * 8;
            int gr = row0 + r;
            u16x8 v = {0,0,0,0,0,0,0,0};
            if (gr < M) v = *(const u16x8*)(A + (size_t)gr * lda + k0 + cp);
            *(u16x8*)&Alds[r][cp] = v;
        }
        if (t < 128) {
            int r = t >> 2, cp = (t & 3) * 8;
            *(u16x8*)&Blds[r][cp] = *(const u16x8*)(B + (size_t)r * ldb + k0 + cp);
        }
        __syncthreads();
        bf16x8 af[2], bfr[2];
        #pragma unroll
        for (int it = 0; it < 2; it++) af[it] = *(const bf16x8*)&Alds[wid * 32 + it * 16 + l16][quad * 8];
        #pragma unroll
        for (int jt = 0; jt < 2; jt++) bfr[jt] = *(const bf16x8*)&Blds[jt * 16 + l16][quad * 8];
        #pragma unroll
        for (int it = 0; it < 2; it++)
            #pragma unroll
            for (int jt = 0; jt < 2; jt++)
                acc[it][jt] = __builtin_amdgcn_mfma_f32_16x16x32_bf16(af[it], bfr[jt], acc[it][jt], 0, 0, 0);
        __syncthreads();
    }
    #pragma unroll
    for (int it = 0; it < 2; it++) {
        int gr0 = row0 + wid * 32 + it * 16 + quad * 4;
        #pragma unroll
        for (int jt = 0; jt < 2; jt++) {
            int gc = jt * 16 + l16;
            #pragma unroll
            for (int r = 0; r < 4; r++) {
                int gr = gr0 + r;
                if (gr < M) C[(size_t)gr * 32 + gc] = acc[it][jt][r];
            }
        }
    }
}

// ---------------- attention scalars (H=4, C=64), bf16 h: one wave/node, 8B loads ----
__global__ __launch_bounds__(256) void al_kernel(const u16* __restrict__ h,
        const float* __restrict__ a_s, const float* __restrict__ a_d,
        float* __restrict__ als, float* __restrict__ ald, int N) {
    const int t = threadIdx.x, wid = t >> 6, lane = t & 63;
    const f32x4 as4 = *(const f32x4*)&a_s[lane * 4];
    const f32x4 ad4 = *(const f32x4*)&a_d[lane * 4];
    #pragma unroll
    for (int u = 0; u < 2; u++) {
        const int n = blockIdx.x * 8 + wid * 2 + u;
        if (n >= N) return;
        const u16x4 hv = *(const u16x4*)&h[(size_t)n * 256 + lane * 4];
        float ps = 0.f, pd = 0.f;
        #pragma unroll
        for (int c = 0; c < 4; c++) {
            const float f = bs2f(hv[c]);
            ps = fmaf(f, as4[c], ps);
            pd = fmaf(f, ad4[c], pd);
        }
        #pragma unroll
        for (int off = 8; off >= 1; off >>= 1) {
            ps += __shfl_xor(ps, off, 16);
            pd += __shfl_xor(pd, off, 16);
        }
        if ((lane & 15) == 0) {
            als[n * 4 + (lane >> 4)] = ps;
            ald[n * 4 + (lane >> 4)] = pd;
        }
    }
}

__global__ __launch_bounds__(256) void al3_kernel(const float* __restrict__ h3,
        const float* __restrict__ a_s, const float* __restrict__ a_d,
        float* __restrict__ als, float* __restrict__ ald, int N) {
    int t = threadIdx.x, wid = t >> 6, lane = t & 63;
    int c = lane & 31, half = lane >> 5;
    float as = a_s[c], ad = a_d[c];
    int n = blockIdx.x * 8 + wid * 2 + half;
    if (n >= N) return;
    float hv = h3[(size_t)n * 32 + c];
    float ps = hv * as, pd = hv * ad;
    for (int off = 16; off >= 1; off >>= 1) { ps += __shfl_down(ps, off, 32); pd += __shfl_down(pd, off, 32); }
    if (c == 0) { als[n] = ps; ald[n] = pd; }
}

// ---------------- softmax-aggregation (H=4, C=64): one wave per node, bf16 h ----------------
// Single pass (deg<=64): e in registers, (s,alpha) staged in LDS once.
// Gather: 16B/lane, 32 lanes per neighbor row; halves own alternate edges ->
// 8 independent loads in flight per wave. Streaming fallback for deg>64.
__global__ __launch_bounds__(256) void agg_kernel(const u16* __restrict__ hbuf,
        const float* __restrict__ als, const float* __restrict__ ald,
        const int* __restrict__ ptr, const int* __restrict__ csr,
        const float* __restrict__ bias, u16* __restrict__ act, int N) {
    __shared__ float al_lds[4][64][4];
    __shared__ int   s_lds[4][64];
    const int t = threadIdx.x, wid = t >> 6, lane = t & 63;
    const int i = blockIdx.x * 4 + wid;
    if (i >= N) return;
    const int start = ptr[i], end = ptr[i + 1];
    const int deg = end - start;
    const int col8 = lane & 31;          // which 8-feature chunk of the 256-wide row
    const int half = lane >> 5;
    const int head8 = col8 >> 3;         // head owning this lane's 8 features

    const f32x4 aldv = *(const f32x4*)&ald[(size_t)i * 4];
    const f32x4 alsv = *(const f32x4*)&als[(size_t)i * 4];
    f32x4 eself;
    #pragma unroll
    for (int hh = 0; hh < 4; hh++) eself[hh] = lrelu(alsv[hh] + aldv[hh]);

    float acc[8];
    f32x4 mx, inv;

    if (deg <= 64) {
        // ---- single-pass softmax ----
        int sreg = 0;
        f32x4 ev;
        #pragma unroll
        for (int hh = 0; hh < 4; hh++) ev[hh] = -1e30f;
        if (lane < deg) {
            sreg = csr[start + lane];
            const f32x4 a = *(const f32x4*)&als[(size_t)sreg * 4];
            #pragma unroll
            for (int hh = 0; hh < 4; hh++) ev[hh] = lrelu(a[hh] + aldv[hh]);
        }
        #pragma unroll
        for (int hh = 0; hh < 4; hh++) mx[hh] = fmaxf(eself[hh], ev[hh]);
        #pragma unroll
        for (int off = 32; off >= 1; off >>= 1) {
            #pragma unroll
            for (int hh = 0; hh < 4; hh++) mx[hh] = fmaxf(mx[hh], __shfl_xor(mx[hh], off));
        }
        f32x4 sm, av;
        #pragma unroll
        for (int hh = 0; hh < 4; hh++) {
            av[hh] = (lane < deg) ? expf(ev[hh] - mx[hh]) : 0.f;
            sm[hh] = av[hh] + ((lane == 0) ? expf(eself[hh] - mx[hh]) : 0.f);
        }
        #pragma unroll
        for (int off = 32; off >= 1; off >>= 1) {
            #pragma unroll
            for (int hh = 0; hh < 4; hh++) sm[hh] += __shfl_xor(sm[hh], off);
        }
        #pragma unroll
        for (int hh = 0; hh < 4; hh++) inv[hh] = 1.f / (sm[hh] + 1e-16f);
        #pragma unroll
        for (int hh = 0; hh < 4; hh++) av[hh] *= inv[hh];
        *(f32x4*)&al_lds[wid][lane][0] = av;
        s_lds[wid][lane] = sreg;

        // ---- gather: 16B/lane, halves interleave edges ----
        const u16x8 hrs = *(const u16x8*)&hbuf[(size_t)i * 256 + col8 * 8];
        const float aself = expf(eself[head8] - mx[head8]) * inv[head8];
        #pragma unroll
        for (int c = 0; c < 8; c++) acc[c] = (half == 0) ? aself * bs2f(hrs[c]) : 0.f;

        int k = half;
        for (; k + 6 < deg; k += 8) {
            const int s0 = s_lds[wid][k],     s1 = s_lds[wid][k + 2];
            const int s2 = s_lds[wid][k + 4], s3 = s_lds[wid][k + 6];
            const float a0 = al_lds[wid][k][head8],     a1 = al_lds[wid][k + 2][head8];
            const float a2 = al_lds[wid][k + 4][head8], a3 = al_lds[wid][k + 6][head8];
            const u16x8 h0 = *(const u16x8*)&hbuf[(size_t)s0 * 256 + col8 * 8];
            const u16x8 h1 = *(const u16x8*)&hbuf[(size_t)s1 * 256 + col8 * 8];
            const u16x8 h2 = *(const u16x8*)&hbuf[(size_t)s2 * 256 + col8 * 8];
            const u16x8 h3v = *(const u16x8*)&hbuf[(size_t)s3 * 256 + col8 * 8];
            #pragma unroll
            for (int c = 0; c < 8; c++) {
                acc[c] = fmaf(a0, bs2f(h0[c]), acc[c]);
                acc[c] = fmaf(a1, bs2f(h1[c]), acc[c]);
                acc[c] = fmaf(a2, bs2f(h2[c]), acc[c]);
                acc[c] = fmaf(a3, bs2f(h3v[c]), acc[c]);
            }
        }
        for (; k < deg; k += 2) {
            const int s = s_lds[wid][k];
            const float a = al_lds[wid][k][head8];
            const u16x8 hr = *(const u16x8*)&hbuf[(size_t)s * 256 + col8 * 8];
            #pragma unroll
            for (int c = 0; c < 8; c++) acc[c] = fmaf(a, bs2f(hr[c]), acc[c]);
        }
    } else {
        // ---- streaming fallback (rare) ----
        mx = eself;
        for (int j = start + lane; j < end; j += 64) {
            int s = csr[j];
            const f32x4 a = *(const f32x4*)&als[(size_t)s * 4];
            #pragma unroll
            for (int hh = 0; hh < 4; hh++) mx[hh] = fmaxf(mx[hh], lrelu(a[hh] + aldv[hh]));
        }
        #pragma unroll
        for (int off = 32; off >= 1; off >>= 1) {
            #pragma unroll
            for (int hh = 0; hh < 4; hh++) mx[hh] = fmaxf(mx[hh], __shfl_xor(mx[hh], off));
        }
        f32x4 sm;
        #pragma unroll
        for (int hh = 0; hh < 4; hh++) sm[hh] = (lane == 0) ? expf(eself[hh] - mx[hh]) : 0.f;
        for (int j = start + lane; j < end; j += 64) {
            int s = csr[j];
            const f32x4 a = *(const f32x4*)&als[(size_t)s * 4];
            #pragma unroll
            for (int hh = 0; hh < 4; hh++) sm[hh] += expf(lrelu(a[hh] + aldv[hh]) - mx[hh]);
        }
        #pragma unroll
        for (int off = 32; off >= 1; off >>= 1) {
            #pragma unroll
            for (int hh = 0; hh < 4; hh++) sm[hh] += __shfl_xor(sm[hh], off);
        }
        #pragma unroll
        for (int hh = 0; hh < 4; hh++) inv[hh] = 1.f / (sm[hh] + 1e-16f);

        const u16x8 hrs = *(const u16x8*)&hbuf[(size_t)i * 256 + col8 * 8];
        const float aself = expf(eself[head8] - mx[head8]) * inv[head8];
        #pragma unroll
        for (int c = 0; c < 8; c++) acc[c] = (half == 0) ? aself * bs2f(hrs[c]) : 0.f;

        for (int base = start; base < end; base += 64) {
            const int n64 = min(64, end - base);
            const int j = base + lane;
            int sreg = 0;
            if (j < end) {
                sreg = csr[j];
                const f32x4 a = *(const f32x4*)&als[(size_t)sreg * 4];
                f32x4 alpha;
                #pragma unroll
                for (int hh = 0; hh < 4; hh++)
                    alpha[hh] = expf(lrelu(a[hh] + aldv[hh]) - mx[hh]) * inv[hh];
                *(f32x4*)&al_lds[wid][lane][0] = alpha;
            }
            s_lds[wid][lane] = sreg;
            for (int k = half; k < n64; k += 2) {
                const int s = s_lds[wid][k];
                const float a = al_lds[wid][k][head8];
                const u16x8 hr = *(const u16x8*)&hbuf[(size_t)s * 256 + col8 * 8];
                #pragma unroll
                for (int c = 0; c < 8; c++) acc[c] = fmaf(a, bs2f(hr[c]), acc[c]);
            }
        }
    }

    // combine halves, bias + ReLU, 16B store by half 0
    #pragma unroll
    for (int c = 0; c < 8; c++) acc[c] += __shfl_down(acc[c], 32);
    if (half == 0) {
        const f32x4 bv0 = *(const f32x4*)&bias[col8 * 8];
        const f32x4 bv1 = *(const f32x4*)&bias[col8 * 8 + 4];
        u16x8 o;
        #pragma unroll
        for (int c = 0; c < 4; c++) o[c] = f2bs(fmaxf(acc[c] + bv0[c], 0.f));
        #pragma unroll
        for (int c = 4; c < 8; c++) o[c] = f2bs(fmaxf(acc[c] + bv1[c - 4], 0.f));
        *(u16x8*)&act[(size_t)i * 256 + col8 * 8] = o;
    }
}

// ---------------- layer-3 aggregation (H=1, C=32): one wave/node, halves split edges ----
__global__ __launch_bounds__(256) void agg3_kernel(const float* __restrict__ h3,
        const float* __restrict__ als, const float* __restrict__ ald,
        const int* __restrict__ ptr, const int* __restrict__ csr,
        const float* __restrict__ bias, float* __restrict__ out_n, int N) {
    __shared__ float a_lds[4][64];
    __shared__ int   s_lds3[4][64];
    const int t = threadIdx.x, wid = t >> 6, lane = t & 63;
    const int col = lane & 31, half = lane >> 5;
    const int i = blockIdx.x * 4 + wid;
    if (i >= N) return;
    const int start = ptr[i], end = ptr[i + 1];
    const int deg = end - start;
    const float aldv = ald[i];
    const float e0 = lrelu(als[i] + aldv);
    float acc = 0.f;

    if (deg <= 64) {
        // ---- single-pass fast path ----
        int sreg = 0; float ev = -1e30f;
        if (lane < deg) { sreg = csr[start + lane]; ev = lrelu(als[sreg] + aldv); }
        float mx = fmaxf(e0, ev);
        #pragma unroll
        for (int off = 32; off >= 1; off >>= 1) mx = fmaxf(mx, __shfl_xor(mx, off));
        float ex = (lane < deg) ? expf(ev - mx) : 0.f;
        float sm = ex + ((lane == 0) ? expf(e0 - mx) : 0.f);
        #pragma unroll
        for (int off = 32; off >= 1; off >>= 1) sm += __shfl_xor(sm, off);
        const float inv = 1.f / (sm + 1e-16f);
        a_lds[wid][lane] = ex * inv;
        s_lds3[wid][lane] = sreg;
        if (half == 0) acc = expf(e0 - mx) * inv * h3[(size_t)i * 32 + col];

        // halves own alternate edges; 4 loads in flight per half (8/wave)
        int k = half;
        for (; k + 6 < deg; k += 8) {
            const int s0 = s_lds3[wid][k],     s1 = s_lds3[wid][k + 2];
            const int s2 = s_lds3[wid][k + 4], s3 = s_lds3[wid][k + 6];
            const float a0 = a_lds[wid][k],     a1 = a_lds[wid][k + 2];
            const float a2 = a_lds[wid][k + 4], a3 = a_lds[wid][k + 6];
            const float v0 = h3[(size_t)s0 * 32 + col];
            const float v1 = h3[(size_t)s1 * 32 + col];
            const float v2 = h3[(size_t)s2 * 32 + col];
            const float v3 = h3[(size_t)s3 * 32 + col];
            acc = fmaf(a0, v0, acc); acc = fmaf(a1, v1, acc);
            acc = fmaf(a2, v2, acc); acc = fmaf(a3, v3, acc);
        }
        for (; k < deg; k += 2)
            acc = fmaf(a_lds[wid][k], h3[(size_t)s_lds3[wid][k] * 32 + col], acc);
    } else {
        // ---- streaming fallback (rare) ----
        float mx = e0;
        for (int j = start + lane; j < end; j += 64)
            mx = fmaxf(mx, lrelu(als[csr[j]] + aldv));
        #pragma unroll
        for (int off = 32; off >= 1; off >>= 1) mx = fmaxf(mx, __shfl_xor(mx, off));
        float sm = (lane == 0) ? expf(e0 - mx) : 0.f;
        for (int j = start + lane; j < end; j += 64)
            sm += expf(lrelu(als[csr[j]] + aldv) - mx);
        #pragma unroll
        for (int off = 32; off >= 1; off >>= 1) sm += __shfl_xor(sm, off);
        const float inv = 1.f / (sm + 1e-16f);
        if (half == 0) acc = expf(e0 - mx) * inv * h3[(size_t)i * 32 + col];
        for (int base = start; base < end; base += 64) {
            const int n64 = min(64, end - base);
            const int j = base + lane;
            int sreg = 0; float av = 0.f;
            if (j < end) {
                sreg = csr[j];
                av = expf(lrelu(als[sreg] + aldv) - mx) * inv;
            }
            a_lds[wid][lane] = av;
            s_lds3[wid][lane] = sreg;
            for (int k = half; k < n64; k += 2)
                acc = fmaf(a_lds[wid][k], h3[(size_t)s_lds3[wid][k] * 32 + col], acc);
        }
    }

    acc += __shfl_down(acc, 32);
    if (half == 0)
        out_n[(size_t)i * 32 + col] = acc + bias[col];   // no ReLU on layer 3
}

// ---------------- deterministic segmented mean pool (batch sorted) ----------------
__global__ __launch_bounds__(256) void pool_kernel(const float* __restrict__ out_n,
        const int* __restrict__ gstart, float* __restrict__ out, int G) {
    const int t = threadIdx.x, wid = t >> 6, lane = t & 63;
    const int col = lane & 31, half = lane >> 5;
    const int g = blockIdx.x * 4 + wid;
    if (g >= G) return;
    const int s = gstart[g], e = gstart[g + 1];
    float acc = 0.f;
    int r = s + half;
    for (; r + 6 < e; r += 8) {
        acc += out_n[(size_t)r * 32 + col];
        acc += out_n[(size_t)(r + 2) * 32 + col];
        acc += out_n[(size_t)(r + 4) * 32 + col];
        acc += out_n[(size_t)(r + 6) * 32 + col];
    }
    for (; r < e; r += 2) acc += out_n[(size_t)r * 32 + col];
    acc += __shfl_down(acc, 32);
    if (half == 0)
        out[g * 32 + col] = acc / fmaxf((float)(e - s), 1.f);
}

extern "C" void kernel_launch(void* const* d_in, const int* in_sizes, int n_in,
                              void* d_out, int out_size, void* d_ws, size_t ws_size,
                              hipStream_t stream) {
    const int N = 50000, E = 800000, G = 512;
    const float* x    = (const float*)d_in[0];
    const int*   ei   = (const int*)d_in[1];
    const int*   batch= (const int*)d_in[2];
    const float* W1   = (const float*)d_in[3];
    const float* as1  = (const float*)d_in[4];
    const float* ad1  = (const float*)d_in[5];
    const float* b1   = (const float*)d_in[6];
    const float* W2   = (const float*)d_in[7];
    const float* as2  = (const float*)d_in[8];
    const float* ad2  = (const float*)d_in[9];
    const float* b2   = (const float*)d_in[10];
    const float* W3   = (const float*)d_in[11];
    const float* as3  = (const float*)d_in[12];
    const float* ad3  = (const float*)d_in[13];
    const float* b3   = (const float*)d_in[14];
    const int* esrc = ei;
    const int* edst = ei + E;

    char* base = (char*)d_ws; size_t off = 0;
    auto alloc = [&](size_t bytes) -> void* {
        void* p = base + off; off = (off + bytes + 255) & ~(size_t)255; return p;
    };
    u16*   hbuf = (u16*)  alloc((size_t)N * 256 * 2);   // GEMM out / messages (bf16)
    u16*   act  = (u16*)  alloc((size_t)N * 256 * 2);   // bf16 activations
    float* h3   = (float*)alloc((size_t)N * 32 * 4);    // layer-3 pre-agg (fp32)
    float* als  = (float*)alloc((size_t)N * 4 * 4);
    float* ald  = (float*)alloc((size_t)N * 4 * 4);
    int*   deg  = (int*)  alloc((size_t)N * 4);
    int*   ptr  = (int*)  alloc((size_t)(N + 1) * 4);
    int*   cur  = (int*)  alloc((size_t)N * 4);
    int*   csr  = (int*)  alloc((size_t)E * 4);
    u16*   Wt   = (u16*)  alloc((size_t)256 * 800 * 2);
    int*   bsum = (int*)  alloc((size_t)64 * 4);
    float* out_n= (float*)alloc((size_t)N * 32 * 4);    // per-node layer-3 output
    int*   gstart=(int*)  alloc((size_t)(G + 1) * 4);
    u16*   xbf  = (u16*)  alloc((size_t)N * 800 * 2);   // bf16-padded x (fits: ~150MB total)

    hipMemsetAsync(deg, 0, (size_t)N * 4, stream);

    // CSR over dst (reused by all 3 layers; self-loop handled via eself term)
    const int nb = (N + 1023) / 1024;
    deg_kernel<<<(E + 255) / 256, 256, 0, stream>>>(edst, deg, E);
    scan_local<<<nb, 1024, 0, stream>>>(deg, ptr, bsum, N);
    scan_carry<<<1, 64, 0, stream>>>(bsum, nb);
    scan_final<<<nb, 1024, 0, stream>>>(deg, ptr, cur, bsum, N);
    fill_kernel<<<(E + 255) / 256, 256, 0, stream>>>(esrc, edst, cur, csr, E);
    bounds_kernel<<<(N + 256) / 256, 256, 0, stream>>>(batch, gstart, N, G);

    dim3 gemmGrid(2, (N + 127) / 128);               // col-block fast axis: L2 A-sharing
    const int aggGrid = (N + 3) / 4;
    // ---- layer 1 (x -> bf16 once, then m97-style global_load_lds GEMM) ----
    transpose_w<<<(256 * 800 + 255) / 256, 256, 0, stream>>>(W1, Wt, 775, 256, 800);
    conv_x<<<(N * 200 + 255) / 256, 256, 0, stream>>>(x, xbf, N);
    gemm_glds<<<gemmGrid, 256, 0, stream>>>(xbf, 800, N, 800, Wt, 800, hbuf, 256);
    al_kernel<<<(N + 7) / 8, 256, 0, stream>>>(hbuf, as1, ad1, als, ald, N);
    agg_kernel<<<aggGrid, 256, 0, stream>>>(hbuf, als, ald, ptr, csr, b1, act, N);
    // ---- layer 2 ----
    transpose_w<<<(256 * 256 + 255) / 256, 256, 0, stream>>>(W2, Wt, 256, 256, 256);
    gemm_glds<<<gemmGrid, 256, 0, stream>>>(act, 256, N, 256, Wt, 256, hbuf, 256);
    al_kernel<<<(N + 7) / 8, 256, 0, stream>>>(hbuf, as2, ad2, als, ald, N);
    agg_kernel<<<aggGrid, 256, 0, stream>>>(hbuf, als, ald, ptr, csr, b2, act, N);
    // ---- layer 3 ----
    transpose_w<<<(32 * 256 + 255) / 256, 256, 0, stream>>>(W3, Wt, 256, 32, 256);
    gemm32<<<(N + 127) / 128, 256, 0, stream>>>(act, 256, N, 256, Wt, 256, h3);
    al3_kernel<<<(N + 7) / 8, 256, 0, stream>>>(h3, as3, ad3, als, ald, N);
    agg3_kernel<<<aggGrid, 256, 0, stream>>>(h3, als, ald, ptr, csr, b3, out_n, N);
    pool_kernel<<<(G + 3) / 4, 256, 0, stream>>>(out_n, gstart, (float*)d_out, G);
}

// Round 8
// 609.484 us; speedup vs baseline: 1.0262x; 1.0262x over previous
//
#include <hip/hip_runtime.h>
#include <hip/hip_bf16.h>

typedef unsigned short u16;
typedef __attribute__((ext_vector_type(4))) unsigned short u16x4;
typedef __attribute__((ext_vector_type(8))) unsigned short u16x8;
typedef __attribute__((ext_vector_type(8))) short bf16x8;
typedef __attribute__((ext_vector_type(4))) float f32x4;

__device__ __forceinline__ u16 f2bs(float f) {
    union { float f; unsigned int u; } x; x.f = f;
    unsigned int r = x.u + 0x7FFFu + ((x.u >> 16) & 1u);   // RNE
    return (u16)(r >> 16);
}
__device__ __forceinline__ float bs2f(u16 u) {
    union { unsigned int u; float f; } x; x.u = ((unsigned int)u) << 16; return x.f;
}
__device__ __forceinline__ float lrelu(float e) { return e >= 0.f ? e : 0.2f * e; }

// async global->LDS; lds dest must be wave-uniform base (HW adds lane*width)
__device__ __forceinline__ void glds16(const void* g, void* l) {
    __builtin_amdgcn_global_load_lds(
        (const __attribute__((address_space(1))) unsigned int*)g,
        (__attribute__((address_space(3))) unsigned int*)l, 16, 0, 0);
}
__device__ __forceinline__ void glds4(const void* g, void* l) {
    __builtin_amdgcn_global_load_lds(
        (const __attribute__((address_space(1))) unsigned int*)g,
        (__attribute__((address_space(3))) unsigned int*)l, 4, 0, 0);
}

// ---------------- CSR build ----------------
__global__ void deg_kernel(const int* __restrict__ dst, int* __restrict__ deg, int E) {
    int i = blockIdx.x * 256 + threadIdx.x;
    if (i < E) atomicAdd(&deg[dst[i]], 1);
}

// hierarchical scan: local (1024/block) -> carry scan -> fixup
__global__ __launch_bounds__(1024) void scan_local(const int* __restrict__ deg,
        int* __restrict__ ptr, int* __restrict__ bsum, int N) {
    __shared__ int wsum[16];
    const int t = threadIdx.x, i = blockIdx.x * 1024 + t;
    const int lane = t & 63, w = t >> 6;
    int v = (i < N) ? deg[i] : 0;
    int x = v;
    #pragma unroll
    for (int off = 1; off < 64; off <<= 1) { int y = __shfl_up(x, off); if (lane >= off) x += y; }
    if (lane == 63) wsum[w] = x;
    __syncthreads();
    if (w == 0) {
        int s = (lane < 16) ? wsum[lane] : 0;
        #pragma unroll
        for (int off = 1; off < 16; off <<= 1) { int y = __shfl_up(s, off); if (lane >= off) s += y; }
        if (lane < 16) wsum[lane] = s;
    }
    __syncthreads();
    int incl = x + (w > 0 ? wsum[w - 1] : 0);
    if (i < N) ptr[i + 1] = incl;            // local inclusive; fixed by scan_final
    if (t == 0) bsum[blockIdx.x] = wsum[15];
}

__global__ __launch_bounds__(64) void scan_carry(int* __restrict__ bsum, int nb) {
    int t = threadIdx.x;
    int v = (t < nb) ? bsum[t] : 0;
    int x = v;
    #pragma unroll
    for (int off = 1; off < 64; off <<= 1) { int y = __shfl_up(x, off); if (t >= off) x += y; }
    if (t < nb) bsum[t] = x - v;             // exclusive
}

__global__ __launch_bounds__(1024) void scan_final(const int* __restrict__ deg,
        int* __restrict__ ptr, int* __restrict__ cur, const int* __restrict__ bsum, int N) {
    int i = blockIdx.x * 1024 + threadIdx.x;
    if (i == 0) ptr[0] = 0;
    if (i < N) {
        int p = ptr[i + 1] + bsum[blockIdx.x];
        ptr[i + 1] = p;
        cur[i] = p - deg[i];
    }
}

__global__ void fill_kernel(const int* __restrict__ src, const int* __restrict__ dst,
        int* __restrict__ cur, int* __restrict__ csr, int E) {
    int i = blockIdx.x * 256 + threadIdx.x;
    if (i < E) { int p = atomicAdd(&cur[dst[i]], 1); csr[p] = src[i]; }
}

// ---------------- graph boundary index (batch is sorted) ----------------
__global__ void bounds_kernel(const int* __restrict__ batch, int* __restrict__ gstart,
        int N, int G) {
    int i = blockIdx.x * 256 + threadIdx.x;
    if (i > N) return;
    if (i == 0) {
        int b0 = batch[0];
        for (int g = 0; g <= b0; g++) gstart[g] = 0;
    } else if (i == N) {
        int bl = batch[N - 1];
        for (int g = bl + 1; g <= G; g++) gstart[g] = N;
    } else {
        int b = batch[i], bp = batch[i - 1];
        for (int g = bp + 1; g <= b; g++) gstart[g] = i;
    }
}

// ---------------- weight transpose: fp32 W[K][Nn] -> bf16 Wt[Nn][KT] (zero-pad k>=K) ----
__global__ void transpose_w(const float* __restrict__ W, u16* __restrict__ Wt,
        int K, int Nn, int KT) {
    int idx = blockIdx.x * 256 + threadIdx.x;
    if (idx >= Nn * KT) return;
    int n = idx / KT, k = idx - n * KT;
    Wt[(size_t)n * KT + k] = (k < K) ? f2bs(W[(size_t)k * Nn + n]) : (u16)0;
}

// ---------------- layer-1 GEMM: C[M,256] bf16 = fp32 A[M,K] @ Wt^T -----------------
// m97 structure with fp32 A staged DIRECTLY via width-4 global_load_lds (x rows are
// 3100B, only 4B-aligned), converted to bf16 at fragment-read time (f2bs, bit-exact
// vs the old conv_x path). Swizzle: LDS float-slot s of tile row r holds global k
// (s ^ ((r&3)<<3)) — applied on the per-lane SOURCE address and matched at read
// (both-sides rule) -> 4-way read conflicts instead of 16. Tail: k>=K redirects the
// source to k=0 (valid floats; B is zero-padded there so contribution is 0 — no OOB,
// no NaN). B path identical to gemm_glds.
__global__ __launch_bounds__(256) void gemm_glds_f32(
        const float* __restrict__ A, int lda, int M, int K, int KT,
        const u16* __restrict__ B, int ldb,
        u16* __restrict__ C, int ldc) {
    __shared__ float Aldsf[128][32];
    __shared__ u16   Blds[128][32];
    const int t = threadIdx.x;
    const int col0 = blockIdx.x * 128;
    const int row0 = blockIdx.y * 128;
    const int wid = t >> 6, lane = t & 63;
    const int wm = wid >> 1, wn = wid & 1;
    const int quad = lane >> 4, l16 = lane & 15;

    f32x4 acc[4][4];
    f32x4 z = {0.f, 0.f, 0.f, 0.f};
    #pragma unroll
    for (int i = 0; i < 4; i++)
        #pragma unroll
        for (int j = 0; j < 4; j++) acc[i][j] = z;

    const int trb = wid * 32 + (lane >> 2);   // B staging row base
    const int arsub = lane >> 5;              // A staging: lane covers row +0/+1
    const int aslot = lane & 31;              // A staging: float slot

    const int kTiles = KT >> 5;
    for (int kt = 0; kt < kTiles; ++kt) {
        const int k0 = kt << 5;
        // ---- B tile: width-16 glds, 2 per wave (swizzled source chunk) ----
        #pragma unroll
        for (int c = 0; c < 2; c++) {
            const int tr = trb + c * 16;
            const int ks = ((lane & 3) ^ ((tr >> 1) & 3)) * 8;
            glds16(B + (size_t)(col0 + tr) * ldb + k0 + ks, &Blds[wid * 32 + c * 16][0]);
        }
        // ---- A tile: width-4 glds, 16 per wave (2 rows each) ----
        #pragma unroll
        for (int c2 = 0; c2 < 16; c2++) {
            const int r = wid * 32 + c2 * 2 + arsub;
            int gra = row0 + r; if (gra > M - 1) gra = M - 1;
            int kk = k0 + (aslot ^ ((r & 3) << 3));
            if (kk >= K) kk = 0;              // B is zero there -> contribution 0
            glds4(A + (size_t)gra * lda + kk, &Aldsf[wid * 32 + c2 * 2][0]);
        }
        __syncthreads();                      // vmcnt drained -> tiles visible
        bf16x8 af[4], bfr[4];
        #pragma unroll
        for (int it = 0; it < 4; it++) {
            const int r = wm * 64 + it * 16 + l16;
            const int off = (quad ^ (r & 3)) << 3;
            const f32x4 lo = *(const f32x4*)&Aldsf[r][off];
            const f32x4 hi = *(const f32x4*)&Aldsf[r][off + 4];
            bf16x8 a;
            #pragma unroll
            for (int u = 0; u < 4; u++) { a[u] = (short)f2bs(lo[u]); a[u + 4] = (short)f2bs(hi[u]); }
            af[it] = a;
        }
        #pragma unroll
        for (int jt = 0; jt < 4; jt++) {
            const int r = wn * 64 + jt * 16 + l16;
            bfr[jt] = *(const bf16x8*)&Blds[r][(quad ^ ((r >> 1) & 3)) * 8];
        }
        #pragma unroll
        for (int it = 0; it < 4; it++)
            #pragma unroll
            for (int jt = 0; jt < 4; jt++)
                acc[it][jt] = __builtin_amdgcn_mfma_f32_16x16x32_bf16(af[it], bfr[jt], acc[it][jt], 0, 0, 0);
        __syncthreads();                      // compute done -> safe to overwrite
    }
    #pragma unroll
    for (int it = 0; it < 4; it++) {
        int gr0 = row0 + wm * 64 + it * 16 + quad * 4;
        #pragma unroll
        for (int jt = 0; jt < 4; jt++) {
            int gc = col0 + wn * 64 + jt * 16 + l16;
            #pragma unroll
            for (int r = 0; r < 4; r++) {
                int gr = gr0 + r;
                if (gr < M) C[(size_t)gr * ldc + gc] = f2bs(acc[it][jt][r]);
            }
        }
    }
}

// ---------------- GEMM: C[M,256] bf16 = A[M,K]bf16 @ Wt^T (layer 2) ----------------
// m97 structure: 128x128 tile, 256 threads, 4 waves of 64x64 (acc[4][4]), BK=32,
// linear [128][32] LDS filled by global_load_lds width=16, 2 barriers per K-step,
// both-sides k-slot XOR swizzle.
__global__ __launch_bounds__(256) void gemm_glds(
        const u16* __restrict__ A, int lda, int M, int K,
        const u16* __restrict__ B, int ldb,
        u16* __restrict__ C, int ldc) {
    __shared__ u16 Alds[128][32];
    __shared__ u16 Blds[128][32];
    const int t = threadIdx.x;
    const int col0 = blockIdx.x * 128;
    const int row0 = blockIdx.y * 128;
    const int wid = t >> 6, lane = t & 63;
    const int wm = wid >> 1, wn = wid & 1;
    const int quad = lane >> 4, l16 = lane & 15;

    f32x4 acc[4][4];
    f32x4 z = {0.f, 0.f, 0.f, 0.f};
    #pragma unroll
    for (int i = 0; i < 4; i++)
        #pragma unroll
        for (int j = 0; j < 4; j++) acc[i][j] = z;

    const int trb = wid * 32 + (lane >> 2);
    const int kTiles = K >> 5;
    for (int kt = 0; kt < kTiles; ++kt) {
        const int k0 = kt << 5;
        #pragma unroll
        for (int c = 0; c < 2; c++) {
            const int tr = trb + c * 16;
            const int ks = ((lane & 3) ^ ((tr >> 1) & 3)) * 8;   // swizzled source chunk
            int gra = row0 + tr; if (gra > M - 1) gra = M - 1;   // clamp: junk rows unused
            glds16(A + (size_t)gra * lda + k0 + ks, &Alds[wid * 32 + c * 16][0]);
            glds16(B + (size_t)(col0 + tr) * ldb + k0 + ks, &Blds[wid * 32 + c * 16][0]);
        }
        __syncthreads();                    // vmcnt drained -> tiles visible
        bf16x8 af[4], bfr[4];
        #pragma unroll
        for (int it = 0; it < 4; it++) {
            const int r = wm * 64 + it * 16 + l16;
            af[it] = *(const bf16x8*)&Alds[r][(quad ^ ((r >> 1) & 3)) * 8];
        }
        #pragma unroll
        for (int jt = 0; jt < 4; jt++) {
            const int r = wn * 64 + jt * 16 + l16;
            bfr[jt] = *(const bf16x8*)&Blds[r][(quad ^ ((r >> 1) & 3)) * 8];
        }
        #pragma unroll
        for (int it = 0; it < 4; it++)
            #pragma unroll
            for (int jt = 0; jt < 4; jt++)
                acc[it][jt] = __builtin_amdgcn_mfma_f32_16x16x32_bf16(af[it], bfr[jt], acc[it][jt], 0, 0, 0);
        __syncthreads();                    // compute done -> safe to overwrite
    }
    #pragma unroll
    for (int it = 0; it < 4; it++) {
        int gr0 = row0 + wm * 64 + it * 16 + quad * 4;
        #pragma unroll
        for (int jt = 0; jt < 4; jt++) {
            int gc = col0 + wn * 64 + jt * 16 + l16;
            #pragma unroll
            for (int r = 0; r < 4; r++) {
                int gr = gr0 + r;
                if (gr < M) C[(size_t)gr * ldc + gc] = f2bs(acc[it][jt][r]);
            }
        }
    }
}

// GEMM for layer3: C[M,32] fp32 = A[M,256]bf16 @ Wt3^T (h3 stays fp32 — tiny)
__global__ __launch_bounds__(256) void gemm32(
        const u16* __restrict__ A, int lda, int M, int K,
        const u16* __restrict__ B, int ldb, float* __restrict__ C) {
    __shared__ u16 Alds[128][40];
    __shared__ u16 Blds[32][40];
    const int t = threadIdx.x;
    const int row0 = blockIdx.x * 128;
    const int wid = t >> 6, lane = t & 63;
    const int quad = lane >> 4, l16 = lane & 15;
    f32x4 acc[2][2];
    f32x4 z = {0.f, 0.f, 0.f, 0.f};
    acc[0][0] = z; acc[0][1] = z; acc[1][0] = z; acc[1][1] = z;
    const int kTiles = K >> 5;
    for (int kt = 0; kt < kTiles; ++kt) {
        const int k0 = kt << 5;
        #pragma unroll
        for (int c = 0; c < 2; c++) {
            int ch = t + c * 256;
            int r = ch >> 2, cp = (ch & 3) * 8;
            int gr = row0 + r;
            u16x8 v = {0,0,0,0,0,0,0,0};
            if (gr < M) v = *(const u16x8*)(A + (size_t)gr * lda + k0 + cp);
            *(u16x8*)&Alds[r][cp] = v;
        }
        if (t < 128) {
            int r = t >> 2, cp = (t & 3) * 8;
            *(u16x8*)&Blds[r][cp] = *(const u16x8*)(B + (size_t)r * ldb + k0 + cp);
        }
        __syncthreads();
        bf16x8 af[2], bfr[2];
        #pragma unroll
        for (int it = 0; it < 2; it++) af[it] = *(const bf16x8*)&Alds[wid * 32 + it * 16 + l16][quad * 8];
        #pragma unroll
        for (int jt = 0; jt < 2; jt++) bfr[jt] = *(const bf16x8*)&Blds[jt * 16 + l16][quad * 8];
        #pragma unroll
        for (int it = 0; it < 2; it++)
            #pragma unroll
            for (int jt = 0; jt < 2; jt++)
                acc[it][jt] = __builtin_amdgcn_mfma_f32_16x16x32_bf16(af[it], bfr[jt], acc[it][jt], 0, 0, 0);
        __syncthreads();
    }
    #pragma unroll
    for (int it = 0; it < 2; it++) {
        int gr0 = row0 + wid * 32 + it * 16 + quad * 4;
        #pragma unroll
        for (int jt = 0; jt < 2; jt++) {
            int gc = jt * 16 + l16;
            #pragma unroll
            for (int r = 0; r < 4; r++) {
                int gr = gr0 + r;
                if (gr < M) C[(size_t)gr * 32 + gc] = acc[it][jt][r];
            }
        }
    }
}

// ---------------- attention scalars (H=4, C=64), bf16 h: one wave/node, 8B loads ----
__global__ __launch_bounds__(256) void al_kernel(const u16* __restrict__ h,
        const float* __restrict__ a_s, const float* __restrict__ a_d,
        float* __restrict__ als, float* __restrict__ ald, int N) {
    const int t = threadIdx.x, wid = t >> 6, lane = t & 63;
    const f32x4 as4 = *(const f32x4*)&a_s[lane * 4];
    const f32x4 ad4 = *(const f32x4*)&a_d[lane * 4];
    #pragma unroll
    for (int u = 0; u < 2; u++) {
        const int n = blockIdx.x * 8 + wid * 2 + u;
        if (n >= N) return;
        const u16x4 hv = *(const u16x4*)&h[(size_t)n * 256 + lane * 4];
        float ps = 0.f, pd = 0.f;
        #pragma unroll
        for (int c = 0; c < 4; c++) {
            const float f = bs2f(hv[c]);
            ps = fmaf(f, as4[c], ps);
            pd = fmaf(f, ad4[c], pd);
        }
        #pragma unroll
        for (int off = 8; off >= 1; off >>= 1) {
            ps += __shfl_xor(ps, off, 16);
            pd += __shfl_xor(pd, off, 16);
        }
        if ((lane & 15) == 0) {
            als[n * 4 + (lane >> 4)] = ps;
            ald[n * 4 + (lane >> 4)] = pd;
        }
    }
}

__global__ __launch_bounds__(256) void al3_kernel(const float* __restrict__ h3,
        const float* __restrict__ a_s, const float* __restrict__ a_d,
        float* __restrict__ als, float* __restrict__ ald, int N) {
    int t = threadIdx.x, wid = t >> 6, lane = t & 63;
    int c = lane & 31, half = lane >> 5;
    float as = a_s[c], ad = a_d[c];
    int n = blockIdx.x * 8 + wid * 2 + half;
    if (n >= N) return;
    float hv = h3[(size_t)n * 32 + c];
    float ps = hv * as, pd = hv * ad;
    for (int off = 16; off >= 1; off >>= 1) { ps += __shfl_down(ps, off, 32); pd += __shfl_down(pd, off, 32); }
    if (c == 0) { als[n] = ps; ald[n] = pd; }
}

// ---------------- softmax-aggregation (H=4, C=64): one wave per node, bf16 h ----------------
// Single pass (deg<=64): e in registers, (s,alpha) staged in LDS once.
// Gather: 16B/lane, 32 lanes per neighbor row; halves own alternate edges ->
// 8 independent loads in flight per wave. Streaming fallback for deg>64.
__global__ __launch_bounds__(256) void agg_kernel(const u16* __restrict__ hbuf,
        const float* __restrict__ als, const float* __restrict__ ald,
        const int* __restrict__ ptr, const int* __restrict__ csr,
        const float* __restrict__ bias, u16* __restrict__ act, int N) {
    __shared__ float al_lds[4][64][4];
    __shared__ int   s_lds[4][64];
    const int t = threadIdx.x, wid = t >> 6, lane = t & 63;
    const int i = blockIdx.x * 4 + wid;
    if (i >= N) return;
    const int start = ptr[i], end = ptr[i + 1];
    const int deg = end - start;
    const int col8 = lane & 31;          // which 8-feature chunk of the 256-wide row
    const int half = lane >> 5;
    const int head8 = col8 >> 3;         // head owning this lane's 8 features

    const f32x4 aldv = *(const f32x4*)&ald[(size_t)i * 4];
    const f32x4 alsv = *(const f32x4*)&als[(size_t)i * 4];
    f32x4 eself;
    #pragma unroll
    for (int hh = 0; hh < 4; hh++) eself[hh] = lrelu(alsv[hh] + aldv[hh]);

    float acc[8];
    f32x4 mx, inv;

    if (deg <= 64) {
        // ---- single-pass softmax ----
        int sreg = 0;
        f32x4 ev;
        #pragma unroll
        for (int hh = 0; hh < 4; hh++) ev[hh] = -1e30f;
        if (lane < deg) {
            sreg = csr[start + lane];
            const f32x4 a = *(const f32x4*)&als[(size_t)sreg * 4];
            #pragma unroll
            for (int hh = 0; hh < 4; hh++) ev[hh] = lrelu(a[hh] + aldv[hh]);
        }
        #pragma unroll
        for (int hh = 0; hh < 4; hh++) mx[hh] = fmaxf(eself[hh], ev[hh]);
        #pragma unroll
        for (int off = 32; off >= 1; off >>= 1) {
            #pragma unroll
            for (int hh = 0; hh < 4; hh++) mx[hh] = fmaxf(mx[hh], __shfl_xor(mx[hh], off));
        }
        f32x4 sm, av;
        #pragma unroll
        for (int hh = 0; hh < 4; hh++) {
            av[hh] = (lane < deg) ? expf(ev[hh] - mx[hh]) : 0.f;
            sm[hh] = av[hh] + ((lane == 0) ? expf(eself[hh] - mx[hh]) : 0.f);
        }
        #pragma unroll
        for (int off = 32; off >= 1; off >>= 1) {
            #pragma unroll
            for (int hh = 0; hh < 4; hh++) sm[hh] += __shfl_xor(sm[hh], off);
        }
        #pragma unroll
        for (int hh = 0; hh < 4; hh++) inv[hh] = 1.f / (sm[hh] + 1e-16f);
        #pragma unroll
        for (int hh = 0; hh < 4; hh++) av[hh] *= inv[hh];
        *(f32x4*)&al_lds[wid][lane][0] = av;
        s_lds[wid][lane] = sreg;

        // ---- gather: 16B/lane, halves interleave edges ----
        const u16x8 hrs = *(const u16x8*)&hbuf[(size_t)i * 256 + col8 * 8];
        const float aself = expf(eself[head8] - mx[head8]) * inv[head8];
        #pragma unroll
        for (int c = 0; c < 8; c++) acc[c] = (half == 0) ? aself * bs2f(hrs[c]) : 0.f;

        int k = half;
        for (; k + 6 < deg; k += 8) {
            const int s0 = s_lds[wid][k],     s1 = s_lds[wid][k + 2];
            const int s2 = s_lds[wid][k + 4], s3 = s_lds[wid][k + 6];
            const float a0 = al_lds[wid][k][head8],     a1 = al_lds[wid][k + 2][head8];
            const float a2 = al_lds[wid][k + 4][head8], a3 = al_lds[wid][k + 6][head8];
            const u16x8 h0 = *(const u16x8*)&hbuf[(size_t)s0 * 256 + col8 * 8];
            const u16x8 h1 = *(const u16x8*)&hbuf[(size_t)s1 * 256 + col8 * 8];
            const u16x8 h2 = *(const u16x8*)&hbuf[(size_t)s2 * 256 + col8 * 8];
            const u16x8 h3v = *(const u16x8*)&hbuf[(size_t)s3 * 256 + col8 * 8];
            #pragma unroll
            for (int c = 0; c < 8; c++) {
                acc[c] = fmaf(a0, bs2f(h0[c]), acc[c]);
                acc[c] = fmaf(a1, bs2f(h1[c]), acc[c]);
                acc[c] = fmaf(a2, bs2f(h2[c]), acc[c]);
                acc[c] = fmaf(a3, bs2f(h3v[c]), acc[c]);
            }
        }
        for (; k < deg; k += 2) {
            const int s = s_lds[wid][k];
            const float a = al_lds[wid][k][head8];
            const u16x8 hr = *(const u16x8*)&hbuf[(size_t)s * 256 + col8 * 8];
            #pragma unroll
            for (int c = 0; c < 8; c++) acc[c] = fmaf(a, bs2f(hr[c]), acc[c]);
        }
    } else {
        // ---- streaming fallback (rare) ----
        mx = eself;
        for (int j = start + lane; j < end; j += 64) {
            int s = csr[j];
            const f32x4 a = *(const f32x4*)&als[(size_t)s * 4];
            #pragma unroll
            for (int hh = 0; hh < 4; hh++) mx[hh] = fmaxf(mx[hh], lrelu(a[hh] + aldv[hh]));
        }
        #pragma unroll
        for (int off = 32; off >= 1; off >>= 1) {
            #pragma unroll
            for (int hh = 0; hh < 4; hh++) mx[hh] = fmaxf(mx[hh], __shfl_xor(mx[hh], off));
        }
        f32x4 sm;
        #pragma unroll
        for (int hh = 0; hh < 4; hh++) sm[hh] = (lane == 0) ? expf(eself[hh] - mx[hh]) : 0.f;
        for (int j = start + lane; j < end; j += 64) {
            int s = csr[j];
            const f32x4 a = *(const f32x4*)&als[(size_t)s * 4];
            #pragma unroll
            for (int hh = 0; hh < 4; hh++) sm[hh] += expf(lrelu(a[hh] + aldv[hh]) - mx[hh]);
        }
        #pragma unroll
        for (int off = 32; off >= 1; off >>= 1) {
            #pragma unroll
            for (int hh = 0; hh < 4; hh++) sm[hh] += __shfl_xor(sm[hh], off);
        }
        #pragma unroll
        for (int hh = 0; hh < 4; hh++) inv[hh] = 1.f / (sm[hh] + 1e-16f);

        const u16x8 hrs = *(const u16x8*)&hbuf[(size_t)i * 256 + col8 * 8];
        const float aself = expf(eself[head8] - mx[head8]) * inv[head8];
        #pragma unroll
        for (int c = 0; c < 8; c++) acc[c] = (half == 0) ? aself * bs2f(hrs[c]) : 0.f;

        for (int base = start; base < end; base += 64) {
            const int n64 = min(64, end - base);
            const int j = base + lane;
            int sreg = 0;
            if (j < end) {
                sreg = csr[j];
                const f32x4 a = *(const f32x4*)&als[(size_t)sreg * 4];
                f32x4 alpha;
                #pragma unroll
                for (int hh = 0; hh < 4; hh++)
                    alpha[hh] = expf(lrelu(a[hh] + aldv[hh]) - mx[hh]) * inv[hh];
                *(f32x4*)&al_lds[wid][lane][0] = alpha;
            }
            s_lds[wid][lane] = sreg;
            for (int k = half; k < n64; k += 2) {
                const int s = s_lds[wid][k];
                const float a = al_lds[wid][k][head8];
                const u16x8 hr = *(const u16x8*)&hbuf[(size_t)s * 256 + col8 * 8];
                #pragma unroll
                for (int c = 0; c < 8; c++) acc[c] = fmaf(a, bs2f(hr[c]), acc[c]);
            }
        }
    }

    // combine halves, bias + ReLU, 16B store by half 0
    #pragma unroll
    for (int c = 0; c < 8; c++) acc[c] += __shfl_down(acc[c], 32);
    if (half == 0) {
        const f32x4 bv0 = *(const f32x4*)&bias[col8 * 8];
        const f32x4 bv1 = *(const f32x4*)&bias[col8 * 8 + 4];
        u16x8 o;
        #pragma unroll
        for (int c = 0; c < 4; c++) o[c] = f2bs(fmaxf(acc[c] + bv0[c], 0.f));
        #pragma unroll
        for (int c = 4; c < 8; c++) o[c] = f2bs(fmaxf(acc[c] + bv1[c - 4], 0.f));
        *(u16x8*)&act[(size_t)i * 256 + col8 * 8] = o;
    }
}

// ---------------- layer-3 aggregation (H=1, C=32): one wave/node, halves split edges ----
__global__ __launch_bounds__(256) void agg3_kernel(const float* __restrict__ h3,
        const float* __restrict__ als, const float* __restrict__ ald,
        const int* __restrict__ ptr, const int* __restrict__ csr,
        const float* __restrict__ bias, float* __restrict__ out_n, int N) {
    __shared__ float a_lds[4][64];
    __shared__ int   s_lds3[4][64];
    const int t = threadIdx.x, wid = t >> 6, lane = t & 63;
    const int col = lane & 31, half = lane >> 5;
    const int i = blockIdx.x * 4 + wid;
    if (i >= N) return;
    const int start = ptr[i], end = ptr[i + 1];
    const int deg = end - start;
    const float aldv = ald[i];
    const float e0 = lrelu(als[i] + aldv);
    float acc = 0.f;

    if (deg <= 64) {
        // ---- single-pass fast path ----
        int sreg = 0; float ev = -1e30f;
        if (lane < deg) { sreg = csr[start + lane]; ev = lrelu(als[sreg] + aldv); }
        float mx = fmaxf(e0, ev);
        #pragma unroll
        for (int off = 32; off >= 1; off >>= 1) mx = fmaxf(mx, __shfl_xor(mx, off));
        float ex = (lane < deg) ? expf(ev - mx) : 0.f;
        float sm = ex + ((lane == 0) ? expf(e0 - mx) : 0.f);
        #pragma unroll
        for (int off = 32; off >= 1; off >>= 1) sm += __shfl_xor(sm, off);
        const float inv = 1.f / (sm + 1e-16f);
        a_lds[wid][lane] = ex * inv;
        s_lds3[wid][lane] = sreg;
        if (half == 0) acc = expf(e0 - mx) * inv * h3[(size_t)i * 32 + col];

        // halves own alternate edges; 4 loads in flight per half (8/wave)
        int k = half;
        for (; k + 6 < deg; k += 8) {
            const int s0 = s_lds3[wid][k],     s1 = s_lds3[wid][k + 2];
            const int s2 = s_lds3[wid][k + 4], s3 = s_lds3[wid][k + 6];
            const float a0 = a_lds[wid][k],     a1 = a_lds[wid][k + 2];
            const float a2 = a_lds[wid][k + 4], a3 = a_lds[wid][k + 6];
            const float v0 = h3[(size_t)s0 * 32 + col];
            const float v1 = h3[(size_t)s1 * 32 + col];
            const float v2 = h3[(size_t)s2 * 32 + col];
            const float v3 = h3[(size_t)s3 * 32 + col];
            acc = fmaf(a0, v0, acc); acc = fmaf(a1, v1, acc);
            acc = fmaf(a2, v2, acc); acc = fmaf(a3, v3, acc);
        }
        for (; k < deg; k += 2)
            acc = fmaf(a_lds[wid][k], h3[(size_t)s_lds3[wid][k] * 32 + col], acc);
    } else {
        // ---- streaming fallback (rare) ----
        float mx = e0;
        for (int j = start + lane; j < end; j += 64)
            mx = fmaxf(mx, lrelu(als[csr[j]] + aldv));
        #pragma unroll
        for (int off = 32; off >= 1; off >>= 1) mx = fmaxf(mx, __shfl_xor(mx, off));
        float sm = (lane == 0) ? expf(e0 - mx) : 0.f;
        for (int j = start + lane; j < end; j += 64)
            sm += expf(lrelu(als[csr[j]] + aldv) - mx);
        #pragma unroll
        for (int off = 32; off >= 1; off >>= 1) sm += __shfl_xor(sm, off);
        const float inv = 1.f / (sm + 1e-16f);
        if (half == 0) acc = expf(e0 - mx) * inv * h3[(size_t)i * 32 + col];
        for (int base = start; base < end; base += 64) {
            const int n64 = min(64, end - base);
            const int j = base + lane;
            int sreg = 0; float av = 0.f;
            if (j < end) {
                sreg = csr[j];
                av = expf(lrelu(als[sreg] + aldv) - mx) * inv;
            }
            a_lds[wid][lane] = av;
            s_lds3[wid][lane] = sreg;
            for (int k = half; k < n64; k += 2)
                acc = fmaf(a_lds[wid][k], h3[(size_t)s_lds3[wid][k] * 32 + col], acc);
        }
    }

    acc += __shfl_down(acc, 32);
    if (half == 0)
        out_n[(size_t)i * 32 + col] = acc + bias[col];   // no ReLU on layer 3
}

// ---------------- deterministic segmented mean pool (batch sorted) ----------------
__global__ __launch_bounds__(256) void pool_kernel(const float* __restrict__ out_n,
        const int* __restrict__ gstart, float* __restrict__ out, int G) {
    const int t = threadIdx.x, wid = t >> 6, lane = t & 63;
    const int col = lane & 31, half = lane >> 5;
    const int g = blockIdx.x * 4 + wid;
    if (g >= G) return;
    const int s = gstart[g], e = gstart[g + 1];
    float acc = 0.f;
    int r = s + half;
    for (; r + 6 < e; r += 8) {
        acc += out_n[(size_t)r * 32 + col];
        acc += out_n[(size_t)(r + 2) * 32 + col];
        acc += out_n[(size_t)(r + 4) * 32 + col];
        acc += out_n[(size_t)(r + 6) * 32 + col];
    }
    for (; r < e; r += 2) acc += out_n[(size_t)r * 32 + col];
    acc += __shfl_down(acc, 32);
    if (half == 0)
        out[g * 32 + col] = acc / fmaxf((float)(e - s), 1.f);
}

extern "C" void kernel_launch(void* const* d_in, const int* in_sizes, int n_in,
                              void* d_out, int out_size, void* d_ws, size_t ws_size,
                              hipStream_t stream) {
    const int N = 50000, E = 800000, G = 512;
    const float* x    = (const float*)d_in[0];
    const int*   ei   = (const int*)d_in[1];
    const int*   batch= (const int*)d_in[2];
    const float* W1   = (const float*)d_in[3];
    const float* as1  = (const float*)d_in[4];
    const float* ad1  = (const float*)d_in[5];
    const float* b1   = (const float*)d_in[6];
    const float* W2   = (const float*)d_in[7];
    const float* as2  = (const float*)d_in[8];
    const float* ad2  = (const float*)d_in[9];
    const float* b2   = (const float*)d_in[10];
    const float* W3   = (const float*)d_in[11];
    const float* as3  = (const float*)d_in[12];
    const float* ad3  = (const float*)d_in[13];
    const float* b3   = (const float*)d_in[14];
    const int* esrc = ei;
    const int* edst = ei + E;

    char* base = (char*)d_ws; size_t off = 0;
    auto alloc = [&](size_t bytes) -> void* {
        void* p = base + off; off = (off + bytes + 255) & ~(size_t)255; return p;
    };
    u16*   hbuf = (u16*)  alloc((size_t)N * 256 * 2);   // GEMM out / messages (bf16)
    u16*   act  = (u16*)  alloc((size_t)N * 256 * 2);   // bf16 activations
    float* h3   = (float*)alloc((size_t)N * 32 * 4);    // layer-3 pre-agg (fp32)
    float* als  = (float*)alloc((size_t)N * 4 * 4);
    float* ald  = (float*)alloc((size_t)N * 4 * 4);
    int*   deg  = (int*)  alloc((size_t)N * 4);
    int*   ptr  = (int*)  alloc((size_t)(N + 1) * 4);
    int*   cur  = (int*)  alloc((size_t)N * 4);
    int*   csr  = (int*)  alloc((size_t)E * 4);
    u16*   Wt   = (u16*)  alloc((size_t)256 * 800 * 2);
    int*   bsum = (int*)  alloc((size_t)64 * 4);
    float* out_n= (float*)alloc((size_t)N * 32 * 4);    // per-node layer-3 output
    int*   gstart=(int*)  alloc((size_t)(G + 1) * 4);

    hipMemsetAsync(deg, 0, (size_t)N * 4, stream);

    // CSR over dst (reused by all 3 layers; self-loop handled via eself term)
    const int nb = (N + 1023) / 1024;
    deg_kernel<<<(E + 255) / 256, 256, 0, stream>>>(edst, deg, E);
    scan_local<<<nb, 1024, 0, stream>>>(deg, ptr, bsum, N);
    scan_carry<<<1, 64, 0, stream>>>(bsum, nb);
    scan_final<<<nb, 1024, 0, stream>>>(deg, ptr, cur, bsum, N);
    fill_kernel<<<(E + 255) / 256, 256, 0, stream>>>(esrc, edst, cur, csr, E);
    bounds_kernel<<<(N + 256) / 256, 256, 0, stream>>>(batch, gstart, N, G);

    dim3 gemmGrid(2, (N + 127) / 128);               // col-block fast axis: L2 A-sharing
    const int aggGrid = (N + 3) / 4;
    // ---- layer 1 (fp32 x staged directly via width-4 global_load_lds) ----
    transpose_w<<<(256 * 800 + 255) / 256, 256, 0, stream>>>(W1, Wt, 775, 256, 800);
    gemm_glds_f32<<<gemmGrid, 256, 0, stream>>>(x, 775, N, 775, 800, Wt, 800, hbuf, 256);
    al_kernel<<<(N + 7) / 8, 256, 0, stream>>>(hbuf, as1, ad1, als, ald, N);
    agg_kernel<<<aggGrid, 256, 0, stream>>>(hbuf, als, ald, ptr, csr, b1, act, N);
    // ---- layer 2 ----
    transpose_w<<<(256 * 256 + 255) / 256, 256, 0, stream>>>(W2, Wt, 256, 256, 256);
    gemm_glds<<<gemmGrid, 256, 0, stream>>>(act, 256, N, 256, Wt, 256, hbuf, 256);
    al_kernel<<<(N + 7) / 8, 256, 0, stream>>>(hbuf, as2, ad2, als, ald, N);
    agg_kernel<<<aggGrid, 256, 0, stream>>>(hbuf, als, ald, ptr, csr, b2, act, N);
    // ---- layer 3 ----
    transpose_w<<<(32 * 256 + 255) / 256, 256, 0, stream>>>(W3, Wt, 256, 32, 256);
    gemm32<<<(N + 127) / 128, 256, 0, stream>>>(act, 256, N, 256, Wt, 256, h3);
    al3_kernel<<<(N + 7) / 8, 256, 0, stream>>>(h3, as3, ad3, als, ald, N);
    agg3_kernel<<<aggGrid, 256, 0, stream>>>(h3, als, ald, ptr, csr, b3, out_n, N);
    pool_kernel<<<(G + 3) / 4, 256, 0, stream>>>(out_n, gstart, (float*)d_out, G);
}